// Round 5
// baseline (104.672 us; speedup 1.0000x reference)
//
#include <hip/hip_runtime.h>

// BISECT ROUND 2: round-0's harness-PROVEN kernel verbatim (fixed 16-trip
// prefetch hot loop, interleaved-4 KNN_ONE, merge, epilogue), with exactly
// ONE change: staging goes through the counting sort by quantized x
// (hist + prefix + atomic scatter) instead of direct indexed stores.
// Selection is min-3 over globally-unique keys => order-independent =>
// this kernel is correct iff the sort produces a true permutation.
//   PASS -> sort correct on HW; rounds 2-4 bug was the per-m restructure.
//   FAIL -> sort machinery is the culprit; revert to round-0 base.

#define NA 4096
#define NB 4096
#define FD 64
#define WPB 8                  // waves per block
#define MPW 4                  // a-points per wave
#define BLOCK (WPB * 64)
#define APB (WPB * MPW)        // 32 a-points per block
#define NBPAD 4352             // 4096 + 256 pad (absorbs prefetch overrun)
#define PADG 0x7FF00000        // pad key: > any real key, < INT_MAX

static __device__ __forceinline__ int med3_i32(int a, int b, int c) {
    int d;
    asm("v_med3_i32 %0, %1, %2, %3" : "=v"(d) : "v"(a), "v"(b), "v"(c));
    return d;
}

static __device__ __forceinline__ int mad_i24(int a, int b, int c) {
    int d;
    asm("v_mad_i32_i24 %0, %1, %2, %3" : "=v"(d) : "v"(a), "v"(b), "v"(c));
    return d;
}

__global__ __launch_bounds__(BLOCK, 8) void knn_gather_kernel(
    const float* __restrict__ a_feats,   // (B, NA, 64)
    const float* __restrict__ b_feats,   // (B, NB, 64)
    const int*   __restrict__ a_coords,  // (B, NA, 3)
    const int*   __restrict__ b_coords,  // (B, NB, 3)
    float* __restrict__ out)             // (B, NA, 128)
{
    __shared__ __align__(16) unsigned s_pb[NBPAD]; // packed x | y<<8 | z<<16
    __shared__ __align__(16) int      s_G[NBPAD];  // (|b|^2 << 12) | idx
    __shared__ int s_xs[129];
    __shared__ int s_hist[128];
    __shared__ int s_cur[128];

    const int batch = blockIdx.y;
    const int tid   = threadIdx.x;

    // ---- counting-sort staging (the ONE change vs round 0) ----
    if (tid < 128) s_hist[tid] = 0;
    if (tid < 256) { s_pb[NB + tid] = 0u; s_G[NB + tid] = PADG; }
    __syncthreads();

    const int* bc = b_coords + (size_t)batch * NB * 3;
    int pbv[8];
#pragma unroll
    for (int k = 0; k < 8; ++k) {
        const int i = tid + (k << 9);
        const int x = bc[3 * i + 0] >> 4;
        const int y = bc[3 * i + 1] >> 4;
        const int z = bc[3 * i + 2] >> 4;
        pbv[k] = x | (y << 8) | (z << 16);
        atomicAdd(&s_hist[x], 1);
    }
    __syncthreads();

    if (tid < 128) s_xs[tid + 1] = s_hist[tid];
    if (tid == 0)  s_xs[0] = 0;
    __syncthreads();
    for (int d = 1; d < 128; d <<= 1) {
        int v = 0;
        if (tid < 128) {
            v = s_xs[tid + 1];
            if (tid >= d) v += s_xs[tid + 1 - d];
        }
        __syncthreads();
        if (tid < 128) s_xs[tid + 1] = v;
        __syncthreads();
    }
    if (tid < 128) s_cur[tid] = s_xs[tid];
    __syncthreads();

#pragma unroll
    for (int k = 0; k < 8; ++k) {
        const int pb  = pbv[k];
        const int x   = pb & 0xFF;
        const int y   = (pb >> 8)  & 0xFF;
        const int z   = (pb >> 16) & 0xFF;
        const int pos = atomicAdd(&s_cur[x], 1);
        s_pb[pos] = (unsigned)pb;
        s_G[pos]  = ((__mul24(x, x) + __mul24(y, y) + __mul24(z, z)) << 12)
                    | (tid + (k << 9));
    }
    __syncthreads();

    // ---- from here on: round-0 kernel VERBATIM ----
    const int wave  = tid >> 6;
    const int lane  = tid & 63;
    const int nbase = blockIdx.x * APB + wave * MPW;

    const int* ac = a_coords + ((size_t)batch * NA + nbase) * 3;
    int pa0, pa1, pa2, pa3;              // packed a coords (no arrays)
    {
        const int x0 = ac[0] >> 4, y0 = ac[1]  >> 4, z0 = ac[2]  >> 4;
        const int x1 = ac[3] >> 4, y1 = ac[4]  >> 4, z1 = ac[5]  >> 4;
        const int x2 = ac[6] >> 4, y2 = ac[7]  >> 4, z2 = ac[8]  >> 4;
        const int x3 = ac[9] >> 4, y3 = ac[10] >> 4, z3 = ac[11] >> 4;
        pa0 = x0 | (y0 << 8) | (z0 << 16);
        pa1 = x1 | (y1 << 8) | (z1 << 16);
        pa2 = x2 | (y2 << 8) | (z2 << 16);
        pa3 = x3 | (y3 << 8) | (z3 << 16);
    }
    const int neg8k = -8192;             // VOP3 can't take literal; keep in reg

    int k0_0 = 0x7FFFFFFF, k1_0 = 0x7FFFFFFF, k2_0 = 0x7FFFFFFF;
    int k0_1 = 0x7FFFFFFF, k1_1 = 0x7FFFFFFF, k2_1 = 0x7FFFFFFF;
    int k0_2 = 0x7FFFFFFF, k1_2 = 0x7FFFFFFF, k2_2 = 0x7FFFFFFF;
    int k0_3 = 0x7FFFFFFF, k1_3 = 0x7FFFFFFF, k2_3 = 0x7FFFFFFF;

    const uint4* pb4 = (const uint4*)s_pb;
    const int4*  G4  = (const int4*)s_G;
    uint4 P = pb4[lane];
    int4  G = G4[lane];

#define KNN_ONE(PJ, GJ)                                              \
    {                                                                \
        const int Pj = (int)(PJ);                                    \
        const int Gj = (GJ);                                         \
        {   const int t   = __builtin_amdgcn_sdot4(pa0, Pj, 0, false); \
            const int key = mad_i24(t, neg8k, Gj);                   \
            const int n0 = min(k0_0, key);                           \
            const int n1 = med3_i32(k0_0, k1_0, key);                \
            const int n2 = med3_i32(k1_0, k2_0, key);                \
            k0_0 = n0; k1_0 = n1; k2_0 = n2; }                       \
        {   const int t   = __builtin_amdgcn_sdot4(pa1, Pj, 0, false); \
            const int key = mad_i24(t, neg8k, Gj);                   \
            const int n0 = min(k0_1, key);                           \
            const int n1 = med3_i32(k0_1, k1_1, key);                \
            const int n2 = med3_i32(k1_1, k2_1, key);                \
            k0_1 = n0; k1_1 = n1; k2_1 = n2; }                       \
        {   const int t   = __builtin_amdgcn_sdot4(pa2, Pj, 0, false); \
            const int key = mad_i24(t, neg8k, Gj);                   \
            const int n0 = min(k0_2, key);                           \
            const int n1 = med3_i32(k0_2, k1_2, key);                \
            const int n2 = med3_i32(k1_2, k2_2, key);                \
            k0_2 = n0; k1_2 = n1; k2_2 = n2; }                       \
        {   const int t   = __builtin_amdgcn_sdot4(pa3, Pj, 0, false); \
            const int key = mad_i24(t, neg8k, Gj);                   \
            const int n0 = min(k0_3, key);                           \
            const int n1 = med3_i32(k0_3, k1_3, key);                \
            const int n2 = med3_i32(k1_3, k2_3, key);                \
            k0_3 = n0; k1_3 = n1; k2_3 = n2; }                       \
    }

#pragma unroll 2
    for (int k = 0; k < 16; ++k) {
        // prefetch next (k=15 reads the pad region -- initialized, discarded)
        const int qn = lane + ((k + 1) << 6);
        const uint4 Pn = pb4[qn];
        const int4  Gn = G4[qn];

        KNN_ONE(P.x, G.x)
        KNN_ONE(P.y, G.y)
        KNN_ONE(P.z, G.z)
        KNN_ONE(P.w, G.w)

        P = Pn; G = Gn;
    }
#undef KNN_ONE

    const float* bfb = b_feats + (size_t)batch * NB * FD;
    int K0[MPW] = {k0_0, k0_1, k0_2, k0_3};
    int K1[MPW] = {k1_0, k1_1, k1_2, k1_3};
    int K2[MPW] = {k2_0, k2_1, k2_2, k2_3};
    const int PA[MPW] = {pa0, pa1, pa2, pa3};

#pragma unroll
    for (int m = 0; m < MPW; ++m) {
        int a0 = K0[m], a1 = K1[m], a2 = K2[m];
#pragma unroll
        for (int d = 1; d < 64; d <<= 1) {
            const int b0 = __shfl_xor(a0, d, 64);
            const int b1 = __shfl_xor(a1, d, 64);
            const int b2 = __shfl_xor(a2, d, 64);
            const int h0 = max(a0, b0);
            const int l1 = min(a1, b1);
            const int c2 = min(a2, b2);
            a0 = min(a0, b0);
            a1 = min(h0, l1);
            a2 = med3_i32(c2, l1, h0);   // = min(c2, max(l1,h0))
        }
        const int aa = __builtin_amdgcn_sdot4(PA[m], PA[m], 0, false); // |a|^2
        const int i0 = a0 & 4095, i1 = a1 & 4095, i2 = a2 & 4095;
        const float d0 = sqrtf((float)((a0 >> 12) + aa)) * (1.0f / 128.0f);
        const float d1 = sqrtf((float)((a1 >> 12) + aa)) * (1.0f / 128.0f);
        const float d2 = sqrtf((float)((a2 >> 12) + aa)) * (1.0f / 128.0f);
        const float w0 = 0.5f - fminf(d0, 0.5f);
        const float w1 = 0.5f - fminf(d1, 0.5f);
        const float w2 = 0.5f - fminf(d2, 0.5f);

        const size_t row = (size_t)batch * NA + (nbase + m);
        const float g = w0 * bfb[i0 * FD + lane]
                      + w1 * bfb[i1 * FD + lane]
                      + w2 * bfb[i2 * FD + lane];
        out[row * 128 + lane]      = a_feats[row * FD + lane];
        out[row * 128 + 64 + lane] = g;
    }
}

extern "C" void kernel_launch(void* const* d_in, const int* in_sizes, int n_in,
                              void* d_out, int out_size, void* d_ws, size_t ws_size,
                              hipStream_t stream) {
    const float* a_feats  = (const float*)d_in[0];
    const float* b_feats  = (const float*)d_in[1];
    const int*   a_coords = (const int*)d_in[2];
    const int*   b_coords = (const int*)d_in[3];
    float* out = (float*)d_out;

    const int B = in_sizes[0] / (NA * FD);
    dim3 grid(NA / APB, B);
    knn_gather_kernel<<<grid, BLOCK, 0, stream>>>(a_feats, b_feats, a_coords,
                                                  b_coords, out);
}

// Round 6
// 94.692 us; speedup vs baseline: 1.1054x; 1.1054x over previous
//
#include <hip/hip_runtime.h>

// B=8, Na=Nb=4096, D=64. Top-3 NN by integer quantized coords (>>4, <128),
// weights 0.5-min(sqrt(d2)/128,0.5), weighted gather of b_feats,
// out = [a_feats | gathered] (B,Na,128) fp32.
//
// key = ((|b|^2 - 2 a.b) << 12) | idx ranks pairs identically to reference
// (d2 order, lower-index tie-break); d2 = (key>>12) + |a|^2.
//
// Structure (round-5 proven skeleton + windowing):
//  - counting sort of b by quantized x (hist + prefix + atomic scatter)
//  - NEW: rank-sort of the block's 32 a-points by x (32 thr x 32 cmp) so
//    each wave's 4 a-points are x-adjacent; wave scans the union window
//    [xmin-16, xmax+17) in x-buckets => ~6 trips instead of 16.
//  - hot loop, k-registers, KNN_ONE, merge butterfly: VERBATIM round 5,
//    only the trip bounds are runtime (klo..khi), addressing unchanged.
//  - exactness: unscanned => |dx|>=17 => d2>=289; if any merged 3rd-best
//    d2 > 288 (or empty window / pad selected), wave-uniform fallback
//    reruns the verbatim fixed-16-trip full scan. ~4e-4 of waves.

#define NA 4096
#define NB 4096
#define FD 64
#define WPB 8                  // waves per block
#define MPW 4                  // a-points per wave
#define BLOCK (WPB * 64)
#define APB (WPB * MPW)        // 32 a-points per block
#define NBPAD 4352             // 4096 + 256 pad (absorbs prefetch overrun)
#define PADG 0x7FF00000        // pad key: > any real key, < INT_MAX
#define WIN 16                 // x-window half-width
#define THRD2 288              // (WIN+1)^2 - 1

static __device__ __forceinline__ int med3_i32(int a, int b, int c) {
    int d;
    asm("v_med3_i32 %0, %1, %2, %3" : "=v"(d) : "v"(a), "v"(b), "v"(c));
    return d;
}

static __device__ __forceinline__ int mad_i24(int a, int b, int c) {
    int d;
    asm("v_mad_i32_i24 %0, %1, %2, %3" : "=v"(d) : "v"(a), "v"(b), "v"(c));
    return d;
}

__global__ __launch_bounds__(BLOCK, 8) void knn_gather_kernel(
    const float* __restrict__ a_feats,   // (B, NA, 64)
    const float* __restrict__ b_feats,   // (B, NB, 64)
    const int*   __restrict__ a_coords,  // (B, NA, 3)
    const int*   __restrict__ b_coords,  // (B, NB, 3)
    float* __restrict__ out)             // (B, NA, 128)
{
    __shared__ __align__(16) unsigned s_pb[NBPAD]; // packed x | y<<8 | z<<16
    __shared__ __align__(16) int      s_G[NBPAD];  // (|b|^2 << 12) | idx
    __shared__ int s_xs[129];
    __shared__ int s_hist[128];
    __shared__ int s_cur[128];
    __shared__ int s_akey[APB];          // (ax<<8)|slot for rank sort
    __shared__ int s_ord[APB];           // rank -> slot

    const int batch  = blockIdx.y;
    const int tid    = threadIdx.x;
    const int nbase0 = blockIdx.x * APB;

    // ---- staging: counting sort of b (proven) + a-key load ----
    if (tid < 128) s_hist[tid] = 0;
    if (tid < 256) { s_pb[NB + tid] = 0u; s_G[NB + tid] = PADG; }
    if (tid < APB) {
        const int ax = a_coords[((size_t)batch * NA + nbase0 + tid) * 3] >> 4;
        s_akey[tid] = (ax << 8) | tid;   // unique keys
    }
    __syncthreads();

    const int* bc = b_coords + (size_t)batch * NB * 3;
    int pbv[8];
#pragma unroll
    for (int k = 0; k < 8; ++k) {
        const int i = tid + (k << 9);
        const int x = bc[3 * i + 0] >> 4;
        const int y = bc[3 * i + 1] >> 4;
        const int z = bc[3 * i + 2] >> 4;
        pbv[k] = x | (y << 8) | (z << 16);
        atomicAdd(&s_hist[x], 1);
    }
    __syncthreads();

    // rank-sort the 32 a-points (reads s_akey, written before barrier above)
    if (tid < APB) {
        const int my = s_akey[tid];
        int r = 0;
#pragma unroll
        for (int j = 0; j < APB; ++j) r += (s_akey[j] < my) ? 1 : 0;
        s_ord[r] = tid;
    }

    if (tid < 128) s_xs[tid + 1] = s_hist[tid];
    if (tid == 0)  s_xs[0] = 0;
    __syncthreads();
    for (int d = 1; d < 128; d <<= 1) {
        int v = 0;
        if (tid < 128) {
            v = s_xs[tid + 1];
            if (tid >= d) v += s_xs[tid + 1 - d];
        }
        __syncthreads();
        if (tid < 128) s_xs[tid + 1] = v;
        __syncthreads();
    }
    if (tid < 128) s_cur[tid] = s_xs[tid];
    __syncthreads();

#pragma unroll
    for (int k = 0; k < 8; ++k) {
        const int pb  = pbv[k];
        const int x   = pb & 0xFF;
        const int y   = (pb >> 8)  & 0xFF;
        const int z   = (pb >> 16) & 0xFF;
        const int pos = atomicAdd(&s_cur[x], 1);
        s_pb[pos] = (unsigned)pb;
        s_G[pos]  = ((__mul24(x, x) + __mul24(y, y) + __mul24(z, z)) << 12)
                    | (tid + (k << 9));
    }
    __syncthreads();

    // ---- per-wave a-point setup via sorted order ----
    const int wave = tid >> 6;
    const int lane = tid & 63;
    const int si0 = s_ord[wave * MPW + 0];
    const int si1 = s_ord[wave * MPW + 1];
    const int si2 = s_ord[wave * MPW + 2];
    const int si3 = s_ord[wave * MPW + 3];

    const int* acb = a_coords + (size_t)batch * NA * 3;
    int pa0, pa1, pa2, pa3;              // packed a coords (no arrays)
    {
        const int r0 = (nbase0 + si0) * 3, r1 = (nbase0 + si1) * 3;
        const int r2 = (nbase0 + si2) * 3, r3 = (nbase0 + si3) * 3;
        const int x0 = acb[r0] >> 4, y0 = acb[r0+1] >> 4, z0 = acb[r0+2] >> 4;
        const int x1 = acb[r1] >> 4, y1 = acb[r1+1] >> 4, z1 = acb[r1+2] >> 4;
        const int x2 = acb[r2] >> 4, y2 = acb[r2+1] >> 4, z2 = acb[r2+2] >> 4;
        const int x3 = acb[r3] >> 4, y3 = acb[r3+1] >> 4, z3 = acb[r3+2] >> 4;
        pa0 = x0 | (y0 << 8) | (z0 << 16);
        pa1 = x1 | (y1 << 8) | (z1 << 16);
        pa2 = x2 | (y2 << 8) | (z2 << 16);
        pa3 = x3 | (y3 << 8) | (z3 << 16);
    }
    const int neg8k = -8192;             // VOP3 can't take literal; keep in reg

    // union window over the wave's 4 (x-adjacent) a-points
    int klo, khi;
    {
        const int ax0 = pa0 & 0xFF, ax1 = pa1 & 0xFF;
        const int ax2 = pa2 & 0xFF, ax3 = pa3 & 0xFF;
        const int xmn = min(min(ax0, ax1), min(ax2, ax3));
        const int xmx = max(max(ax0, ax1), max(ax2, ax3));
        int blo = xmn - WIN;     blo = blo < 0   ? 0   : blo;
        int bhi = xmx + WIN + 1; bhi = bhi > 128 ? 128 : bhi;
        const int lo = s_xs[blo];
        const int hi = s_xs[bhi];
        klo = lo >> 8;                   // 256-entry trips
        khi = (hi + 255) >> 8;           // <= 16
    }

    int k0_0 = 0x7FFFFFFF, k1_0 = 0x7FFFFFFF, k2_0 = 0x7FFFFFFF;
    int k0_1 = 0x7FFFFFFF, k1_1 = 0x7FFFFFFF, k2_1 = 0x7FFFFFFF;
    int k0_2 = 0x7FFFFFFF, k1_2 = 0x7FFFFFFF, k2_2 = 0x7FFFFFFF;
    int k0_3 = 0x7FFFFFFF, k1_3 = 0x7FFFFFFF, k2_3 = 0x7FFFFFFF;

    const uint4* pb4 = (const uint4*)s_pb;
    const int4*  G4  = (const int4*)s_G;
    uint4 P = pb4[lane + (klo << 6)];
    int4  G = G4[lane + (klo << 6)];

#define KNN_ONE(PJ, GJ)                                              \
    {                                                                \
        const int Pj = (int)(PJ);                                    \
        const int Gj = (GJ);                                         \
        {   const int t   = __builtin_amdgcn_sdot4(pa0, Pj, 0, false); \
            const int key = mad_i24(t, neg8k, Gj);                   \
            const int n0 = min(k0_0, key);                           \
            const int n1 = med3_i32(k0_0, k1_0, key);                \
            const int n2 = med3_i32(k1_0, k2_0, key);                \
            k0_0 = n0; k1_0 = n1; k2_0 = n2; }                       \
        {   const int t   = __builtin_amdgcn_sdot4(pa1, Pj, 0, false); \
            const int key = mad_i24(t, neg8k, Gj);                   \
            const int n0 = min(k0_1, key);                           \
            const int n1 = med3_i32(k0_1, k1_1, key);                \
            const int n2 = med3_i32(k1_1, k2_1, key);                \
            k0_1 = n0; k1_1 = n1; k2_1 = n2; }                       \
        {   const int t   = __builtin_amdgcn_sdot4(pa2, Pj, 0, false); \
            const int key = mad_i24(t, neg8k, Gj);                   \
            const int n0 = min(k0_2, key);                           \
            const int n1 = med3_i32(k0_2, k1_2, key);                \
            const int n2 = med3_i32(k1_2, k2_2, key);                \
            k0_2 = n0; k1_2 = n1; k2_2 = n2; }                       \
        {   const int t   = __builtin_amdgcn_sdot4(pa3, Pj, 0, false); \
            const int key = mad_i24(t, neg8k, Gj);                   \
            const int n0 = min(k0_3, key);                           \
            const int n1 = med3_i32(k0_3, k1_3, key);                \
            const int n2 = med3_i32(k1_3, k2_3, key);                \
            k0_3 = n0; k1_3 = n1; k2_3 = n2; }                       \
    }

    // merge all four per-lane triples -> wave top-3 (proven butterfly)
#define MERGE_ALL()                                                  \
    {                                                                \
        int K0[MPW] = {k0_0, k0_1, k0_2, k0_3};                      \
        int K1[MPW] = {k1_0, k1_1, k1_2, k1_3};                      \
        int K2[MPW] = {k2_0, k2_1, k2_2, k2_3};                      \
        _Pragma("unroll")                                            \
        for (int m = 0; m < MPW; ++m) {                              \
            int a0 = K0[m], a1 = K1[m], a2 = K2[m];                  \
            _Pragma("unroll")                                        \
            for (int d = 1; d < 64; d <<= 1) {                       \
                const int b0 = __shfl_xor(a0, d, 64);                \
                const int b1 = __shfl_xor(a1, d, 64);                \
                const int b2 = __shfl_xor(a2, d, 64);                \
                const int h0 = max(a0, b0);                          \
                const int l1 = min(a1, b1);                          \
                const int c2 = min(a2, b2);                          \
                a0 = min(a0, b0);                                    \
                a1 = min(h0, l1);                                    \
                a2 = med3_i32(c2, l1, h0);                           \
            }                                                        \
            A0[m] = a0; A1[m] = a1; A2[m] = a2;                      \
        }                                                            \
    }

    // ---- windowed hot loop: round-5 body, runtime bounds ----
#pragma unroll 2
    for (int k = klo; k < khi; ++k) {
        const int qn = lane + ((k + 1) << 6);   // prefetch (pads absorb k=15)
        const uint4 Pn = pb4[qn];
        const int4  Gn = G4[qn];

        KNN_ONE(P.x, G.x)
        KNN_ONE(P.y, G.y)
        KNN_ONE(P.z, G.z)
        KNN_ONE(P.w, G.w)

        P = Pn; G = Gn;
    }

    const int PA[MPW] = {pa0, pa1, pa2, pa3};
    int AA[MPW];
#pragma unroll
    for (int m = 0; m < MPW; ++m)
        AA[m] = __builtin_amdgcn_sdot4(PA[m], PA[m], 0, false);  // |a|^2

    int A0[MPW], A1[MPW], A2[MPW];
    MERGE_ALL()

    // ---- exactness fallback (wave-uniform, ~4e-4 of waves) ----
    bool bad = false;
#pragma unroll
    for (int m = 0; m < MPW; ++m)
        bad = bad | ((unsigned)((A2[m] >> 12) + AA[m]) > (unsigned)THRD2);
    if (__any(bad)) {
        k0_0 = 0x7FFFFFFF; k1_0 = 0x7FFFFFFF; k2_0 = 0x7FFFFFFF;
        k0_1 = 0x7FFFFFFF; k1_1 = 0x7FFFFFFF; k2_1 = 0x7FFFFFFF;
        k0_2 = 0x7FFFFFFF; k1_2 = 0x7FFFFFFF; k2_2 = 0x7FFFFFFF;
        k0_3 = 0x7FFFFFFF; k1_3 = 0x7FFFFFFF; k2_3 = 0x7FFFFFFF;
        P = pb4[lane];
        G = G4[lane];
#pragma unroll 2
        for (int k = 0; k < 16; ++k) {          // verbatim round-5 full scan
            const int qn = lane + ((k + 1) << 6);
            const uint4 Pn = pb4[qn];
            const int4  Gn = G4[qn];
            KNN_ONE(P.x, G.x)
            KNN_ONE(P.y, G.y)
            KNN_ONE(P.z, G.z)
            KNN_ONE(P.w, G.w)
            P = Pn; G = Gn;
        }
        MERGE_ALL()
    }
#undef KNN_ONE
#undef MERGE_ALL

    // ---- epilogue: weighted gather + store (row via sorted index) ----
    const float* bfb = b_feats + (size_t)batch * NB * FD;
    const int SI[MPW] = {si0, si1, si2, si3};

#pragma unroll
    for (int m = 0; m < MPW; ++m) {
        const int a0 = A0[m], a1 = A1[m], a2 = A2[m];
        const int aa = AA[m];
        const int i0 = a0 & 4095, i1 = a1 & 4095, i2 = a2 & 4095;
        const float d0 = sqrtf((float)((a0 >> 12) + aa)) * (1.0f / 128.0f);
        const float d1 = sqrtf((float)((a1 >> 12) + aa)) * (1.0f / 128.0f);
        const float d2 = sqrtf((float)((a2 >> 12) + aa)) * (1.0f / 128.0f);
        const float w0 = 0.5f - fminf(d0, 0.5f);
        const float w1 = 0.5f - fminf(d1, 0.5f);
        const float w2 = 0.5f - fminf(d2, 0.5f);

        const size_t row = (size_t)batch * NA + (nbase0 + SI[m]);
        const float g = w0 * bfb[i0 * FD + lane]
                      + w1 * bfb[i1 * FD + lane]
                      + w2 * bfb[i2 * FD + lane];
        out[row * 128 + lane]      = a_feats[row * FD + lane];
        out[row * 128 + 64 + lane] = g;
    }
}

extern "C" void kernel_launch(void* const* d_in, const int* in_sizes, int n_in,
                              void* d_out, int out_size, void* d_ws, size_t ws_size,
                              hipStream_t stream) {
    const float* a_feats  = (const float*)d_in[0];
    const float* b_feats  = (const float*)d_in[1];
    const int*   a_coords = (const int*)d_in[2];
    const int*   b_coords = (const int*)d_in[3];
    float* out = (float*)d_out;

    const int B = in_sizes[0] / (NA * FD);
    dim3 grid(NA / APB, B);
    knn_gather_kernel<<<grid, BLOCK, 0, stream>>>(a_feats, b_feats, a_coords,
                                                  b_coords, out);
}

// Round 7
// 91.860 us; speedup vs baseline: 1.1395x; 1.0308x over previous
//
#include <hip/hip_runtime.h>

// B=8, Na=Nb=4096, D=64. Top-3 NN by integer quantized coords (>>4, <128),
// weights 0.5-min(sqrt(d2)/128,0.5), weighted gather of b_feats,
// out = [a_feats | gathered] (B,Na,128) fp32.
//
// key = ((|b|^2 - 2 a.b) << 12) | idx ranks pairs identically to reference
// (d2 order, lower-index tie-break); d2 = (key>>12) + |a|^2.
//
// Round-7 changes vs proven round 6 (94.7us):
//  - BLOCK 512->1024 (WPB=16, APB=64): halves blocks/batch -> halves the
//    redundant per-block counting sort. Occupancy unchanged (2 blk/CU x 16
//    waves = 32 waves/CU, thread-limited either way).
//  - Hillis-Steele prefix (14 barriers) -> single-wave shfl_up scan by
//    wave 0 (barrier-free; writes s_xs inclusive + s_cur exclusive).
//  - hot loop / KNN_ONE / merge / fallback / epilogue: VERBATIM round 6.

#define NA 4096
#define NB 4096
#define FD 64
#define WPB 16                 // waves per block
#define MPW 4                  // a-points per wave
#define BLOCK (WPB * 64)       // 1024
#define APB (WPB * MPW)        // 64 a-points per block
#define NBPAD 4352             // 4096 + 256 pad (absorbs prefetch overrun)
#define PADG 0x7FF00000        // pad key: > any real key, < INT_MAX
#define WIN 16                 // x-window half-width
#define THRD2 288              // (WIN+1)^2 - 1

static __device__ __forceinline__ int med3_i32(int a, int b, int c) {
    int d;
    asm("v_med3_i32 %0, %1, %2, %3" : "=v"(d) : "v"(a), "v"(b), "v"(c));
    return d;
}

static __device__ __forceinline__ int mad_i24(int a, int b, int c) {
    int d;
    asm("v_mad_i32_i24 %0, %1, %2, %3" : "=v"(d) : "v"(a), "v"(b), "v"(c));
    return d;
}

__global__ __launch_bounds__(BLOCK, 8) void knn_gather_kernel(
    const float* __restrict__ a_feats,   // (B, NA, 64)
    const float* __restrict__ b_feats,   // (B, NB, 64)
    const int*   __restrict__ a_coords,  // (B, NA, 3)
    const int*   __restrict__ b_coords,  // (B, NB, 3)
    float* __restrict__ out)             // (B, NA, 128)
{
    __shared__ __align__(16) unsigned s_pb[NBPAD]; // packed x | y<<8 | z<<16
    __shared__ __align__(16) int      s_G[NBPAD];  // (|b|^2 << 12) | idx
    __shared__ int s_xs[129];
    __shared__ int s_hist[128];
    __shared__ int s_cur[128];
    __shared__ int s_akey[APB];          // (ax<<8)|slot for rank sort
    __shared__ int s_ord[APB];           // rank -> slot

    const int batch  = blockIdx.y;
    const int tid    = threadIdx.x;
    const int nbase0 = blockIdx.x * APB;

    // ---- phase A: init hist/pads + a-key load ----
    if (tid < 128) s_hist[tid] = 0;
    if (tid < 256) { s_pb[NB + tid] = 0u; s_G[NB + tid] = PADG; }
    if (tid < APB) {
        const int ax = a_coords[((size_t)batch * NA + nbase0 + tid) * 3] >> 4;
        s_akey[tid] = (ax << 8) | tid;   // unique keys
    }
    __syncthreads();

    // ---- phase B: histogram (4 pts/thread) + rank-sort of 64 a-points ----
    const int* bc = b_coords + (size_t)batch * NB * 3;
    int pbv[4];
#pragma unroll
    for (int k = 0; k < 4; ++k) {
        const int i = tid + (k << 10);
        const int x = bc[3 * i + 0] >> 4;
        const int y = bc[3 * i + 1] >> 4;
        const int z = bc[3 * i + 2] >> 4;
        pbv[k] = x | (y << 8) | (z << 16);
        atomicAdd(&s_hist[x], 1);
    }
    if (tid < APB) {
        const int my = s_akey[tid];
        int r = 0;
#pragma unroll
        for (int j = 0; j < APB; ++j) r += (s_akey[j] < my) ? 1 : 0;
        s_ord[r] = tid;
    }
    __syncthreads();

    // ---- phase C: barrier-free prefix scan by wave 0 (2 buckets/lane) ----
    if (tid < 64) {
        const int ln = tid;
        const int v0 = s_hist[ln];
        const int v1 = s_hist[ln + 64];
        int s0 = v0, s1 = v1;
#pragma unroll
        for (int d = 1; d < 64; d <<= 1) {
            const int t0 = __shfl_up(s0, d, 64);
            const int t1 = __shfl_up(s1, d, 64);
            if (ln >= d) { s0 += t0; s1 += t1; }
        }
        const int tot0 = __shfl(s0, 63, 64);
        s_xs[ln + 1]  = s0;                  // inclusive
        s_xs[ln + 65] = s1 + tot0;
        if (ln == 0) s_xs[0] = 0;
        s_cur[ln]      = s0 - v0;            // exclusive (scatter cursor)
        s_cur[ln + 64] = s1 + tot0 - v1;
    }
    __syncthreads();

    // ---- phase D: scatter into sorted order ----
#pragma unroll
    for (int k = 0; k < 4; ++k) {
        const int pb  = pbv[k];
        const int x   = pb & 0xFF;
        const int y   = (pb >> 8)  & 0xFF;
        const int z   = (pb >> 16) & 0xFF;
        const int pos = atomicAdd(&s_cur[x], 1);
        s_pb[pos] = (unsigned)pb;
        s_G[pos]  = ((__mul24(x, x) + __mul24(y, y) + __mul24(z, z)) << 12)
                    | (tid + (k << 10));
    }
    __syncthreads();

    // ---- per-wave a-point setup via sorted order ----
    const int wave = tid >> 6;
    const int lane = tid & 63;
    const int si0 = s_ord[wave * MPW + 0];
    const int si1 = s_ord[wave * MPW + 1];
    const int si2 = s_ord[wave * MPW + 2];
    const int si3 = s_ord[wave * MPW + 3];

    const int* acb = a_coords + (size_t)batch * NA * 3;
    int pa0, pa1, pa2, pa3;              // packed a coords (no arrays)
    {
        const int r0 = (nbase0 + si0) * 3, r1 = (nbase0 + si1) * 3;
        const int r2 = (nbase0 + si2) * 3, r3 = (nbase0 + si3) * 3;
        const int x0 = acb[r0] >> 4, y0 = acb[r0+1] >> 4, z0 = acb[r0+2] >> 4;
        const int x1 = acb[r1] >> 4, y1 = acb[r1+1] >> 4, z1 = acb[r1+2] >> 4;
        const int x2 = acb[r2] >> 4, y2 = acb[r2+1] >> 4, z2 = acb[r2+2] >> 4;
        const int x3 = acb[r3] >> 4, y3 = acb[r3+1] >> 4, z3 = acb[r3+2] >> 4;
        pa0 = x0 | (y0 << 8) | (z0 << 16);
        pa1 = x1 | (y1 << 8) | (z1 << 16);
        pa2 = x2 | (y2 << 8) | (z2 << 16);
        pa3 = x3 | (y3 << 8) | (z3 << 16);
    }
    const int neg8k = -8192;             // VOP3 can't take literal; keep in reg

    // union window over the wave's 4 (x-adjacent) a-points
    int klo, khi;
    {
        const int ax0 = pa0 & 0xFF, ax1 = pa1 & 0xFF;
        const int ax2 = pa2 & 0xFF, ax3 = pa3 & 0xFF;
        const int xmn = min(min(ax0, ax1), min(ax2, ax3));
        const int xmx = max(max(ax0, ax1), max(ax2, ax3));
        int blo = xmn - WIN;     blo = blo < 0   ? 0   : blo;
        int bhi = xmx + WIN + 1; bhi = bhi > 128 ? 128 : bhi;
        const int lo = s_xs[blo];
        const int hi = s_xs[bhi];
        klo = lo >> 8;                   // 256-entry trips
        khi = (hi + 255) >> 8;           // <= 16
    }

    int k0_0 = 0x7FFFFFFF, k1_0 = 0x7FFFFFFF, k2_0 = 0x7FFFFFFF;
    int k0_1 = 0x7FFFFFFF, k1_1 = 0x7FFFFFFF, k2_1 = 0x7FFFFFFF;
    int k0_2 = 0x7FFFFFFF, k1_2 = 0x7FFFFFFF, k2_2 = 0x7FFFFFFF;
    int k0_3 = 0x7FFFFFFF, k1_3 = 0x7FFFFFFF, k2_3 = 0x7FFFFFFF;

    const uint4* pb4 = (const uint4*)s_pb;
    const int4*  G4  = (const int4*)s_G;
    uint4 P = pb4[lane + (klo << 6)];
    int4  G = G4[lane + (klo << 6)];

#define KNN_ONE(PJ, GJ)                                              \
    {                                                                \
        const int Pj = (int)(PJ);                                    \
        const int Gj = (GJ);                                         \
        {   const int t   = __builtin_amdgcn_sdot4(pa0, Pj, 0, false); \
            const int key = mad_i24(t, neg8k, Gj);                   \
            const int n0 = min(k0_0, key);                           \
            const int n1 = med3_i32(k0_0, k1_0, key);                \
            const int n2 = med3_i32(k1_0, k2_0, key);                \
            k0_0 = n0; k1_0 = n1; k2_0 = n2; }                       \
        {   const int t   = __builtin_amdgcn_sdot4(pa1, Pj, 0, false); \
            const int key = mad_i24(t, neg8k, Gj);                   \
            const int n0 = min(k0_1, key);                           \
            const int n1 = med3_i32(k0_1, k1_1, key);                \
            const int n2 = med3_i32(k1_1, k2_1, key);                \
            k0_1 = n0; k1_1 = n1; k2_1 = n2; }                       \
        {   const int t   = __builtin_amdgcn_sdot4(pa2, Pj, 0, false); \
            const int key = mad_i24(t, neg8k, Gj);                   \
            const int n0 = min(k0_2, key);                           \
            const int n1 = med3_i32(k0_2, k1_2, key);                \
            const int n2 = med3_i32(k1_2, k2_2, key);                \
            k0_2 = n0; k1_2 = n1; k2_2 = n2; }                       \
        {   const int t   = __builtin_amdgcn_sdot4(pa3, Pj, 0, false); \
            const int key = mad_i24(t, neg8k, Gj);                   \
            const int n0 = min(k0_3, key);                           \
            const int n1 = med3_i32(k0_3, k1_3, key);                \
            const int n2 = med3_i32(k1_3, k2_3, key);                \
            k0_3 = n0; k1_3 = n1; k2_3 = n2; }                       \
    }

    // merge all four per-lane triples -> wave top-3 (proven butterfly)
#define MERGE_ALL()                                                  \
    {                                                                \
        int K0[MPW] = {k0_0, k0_1, k0_2, k0_3};                      \
        int K1[MPW] = {k1_0, k1_1, k1_2, k1_3};                      \
        int K2[MPW] = {k2_0, k2_1, k2_2, k2_3};                      \
        _Pragma("unroll")                                            \
        for (int m = 0; m < MPW; ++m) {                              \
            int a0 = K0[m], a1 = K1[m], a2 = K2[m];                  \
            _Pragma("unroll")                                        \
            for (int d = 1; d < 64; d <<= 1) {                       \
                const int b0 = __shfl_xor(a0, d, 64);                \
                const int b1 = __shfl_xor(a1, d, 64);                \
                const int b2 = __shfl_xor(a2, d, 64);                \
                const int h0 = max(a0, b0);                          \
                const int l1 = min(a1, b1);                          \
                const int c2 = min(a2, b2);                          \
                a0 = min(a0, b0);                                    \
                a1 = min(h0, l1);                                    \
                a2 = med3_i32(c2, l1, h0);                           \
            }                                                        \
            A0[m] = a0; A1[m] = a1; A2[m] = a2;                      \
        }                                                            \
    }

    // ---- windowed hot loop: proven body, runtime bounds ----
#pragma unroll 2
    for (int k = klo; k < khi; ++k) {
        const int qn = lane + ((k + 1) << 6);   // prefetch (pads absorb k=15)
        const uint4 Pn = pb4[qn];
        const int4  Gn = G4[qn];

        KNN_ONE(P.x, G.x)
        KNN_ONE(P.y, G.y)
        KNN_ONE(P.z, G.z)
        KNN_ONE(P.w, G.w)

        P = Pn; G = Gn;
    }

    const int PA[MPW] = {pa0, pa1, pa2, pa3};
    int AA[MPW];
#pragma unroll
    for (int m = 0; m < MPW; ++m)
        AA[m] = __builtin_amdgcn_sdot4(PA[m], PA[m], 0, false);  // |a|^2

    int A0[MPW], A1[MPW], A2[MPW];
    MERGE_ALL()

    // ---- exactness fallback (wave-uniform, rare) ----
    bool bad = false;
#pragma unroll
    for (int m = 0; m < MPW; ++m)
        bad = bad | ((unsigned)((A2[m] >> 12) + AA[m]) > (unsigned)THRD2);
    if (__any(bad)) {
        k0_0 = 0x7FFFFFFF; k1_0 = 0x7FFFFFFF; k2_0 = 0x7FFFFFFF;
        k0_1 = 0x7FFFFFFF; k1_1 = 0x7FFFFFFF; k2_1 = 0x7FFFFFFF;
        k0_2 = 0x7FFFFFFF; k1_2 = 0x7FFFFFFF; k2_2 = 0x7FFFFFFF;
        k0_3 = 0x7FFFFFFF; k1_3 = 0x7FFFFFFF; k2_3 = 0x7FFFFFFF;
        P = pb4[lane];
        G = G4[lane];
#pragma unroll 2
        for (int k = 0; k < 16; ++k) {          // verbatim full scan
            const int qn = lane + ((k + 1) << 6);
            const uint4 Pn = pb4[qn];
            const int4  Gn = G4[qn];
            KNN_ONE(P.x, G.x)
            KNN_ONE(P.y, G.y)
            KNN_ONE(P.z, G.z)
            KNN_ONE(P.w, G.w)
            P = Pn; G = Gn;
        }
        MERGE_ALL()
    }
#undef KNN_ONE
#undef MERGE_ALL

    // ---- epilogue: weighted gather + store (row via sorted index) ----
    const float* bfb = b_feats + (size_t)batch * NB * FD;
    const int SI[MPW] = {si0, si1, si2, si3};

#pragma unroll
    for (int m = 0; m < MPW; ++m) {
        const int a0 = A0[m], a1 = A1[m], a2 = A2[m];
        const int aa = AA[m];
        const int i0 = a0 & 4095, i1 = a1 & 4095, i2 = a2 & 4095;
        const float d0 = sqrtf((float)((a0 >> 12) + aa)) * (1.0f / 128.0f);
        const float d1 = sqrtf((float)((a1 >> 12) + aa)) * (1.0f / 128.0f);
        const float d2 = sqrtf((float)((a2 >> 12) + aa)) * (1.0f / 128.0f);
        const float w0 = 0.5f - fminf(d0, 0.5f);
        const float w1 = 0.5f - fminf(d1, 0.5f);
        const float w2 = 0.5f - fminf(d2, 0.5f);

        const size_t row = (size_t)batch * NA + (nbase0 + SI[m]);
        const float g = w0 * bfb[i0 * FD + lane]
                      + w1 * bfb[i1 * FD + lane]
                      + w2 * bfb[i2 * FD + lane];
        out[row * 128 + lane]      = a_feats[row * FD + lane];
        out[row * 128 + 64 + lane] = g;
    }
}

extern "C" void kernel_launch(void* const* d_in, const int* in_sizes, int n_in,
                              void* d_out, int out_size, void* d_ws, size_t ws_size,
                              hipStream_t stream) {
    const float* a_feats  = (const float*)d_in[0];
    const float* b_feats  = (const float*)d_in[1];
    const int*   a_coords = (const int*)d_in[2];
    const int*   b_coords = (const int*)d_in[3];
    float* out = (float*)d_out;

    const int B = in_sizes[0] / (NA * FD);
    dim3 grid(NA / APB, B);
    knn_gather_kernel<<<grid, BLOCK, 0, stream>>>(a_feats, b_feats, a_coords,
                                                  b_coords, out);
}